// Round 7
// baseline (70.086 us; speedup 1.0000x reference)
//
#include <hip/hip_runtime.h>
#include <math.h>

#define NB 16
#define NQ 900
#define NC 80
#define EPSV 1e-7f
#define IOU_THR 0.1f
#define SPB 16              // students per block
#define CHB 57              // blocks per batch (57*16 = 912 >= 900)
#define NBLK (NB * CHB)     // 912

__device__ __forceinline__ float sigm(float x) { return 1.0f / (1.0f + __expf(-x)); }

// ---- K1: IoU argmax + cnt scatter + BCE/conf + last-block finalize ----
__global__ __launch_bounds__(256) void k_main(
    const float* __restrict__ s_logits,
    const float* __restrict__ s_boxes,
    const float* __restrict__ t_logits,
    const float* __restrict__ t_boxes,
    const int*   __restrict__ tn_p,
    int*    __restrict__ g_cnt,     // [NB*NQ] zeroed by memset node
    int*    done,                   // [1]     zeroed by memset node
    float*  __restrict__ g_v,       // [NB*NQ] flag-gated 5*l1+2*(1-giou), else 0
    float2* __restrict__ g_part,    // [NBLK]  (bce_sum, conf_any)
    float*  __restrict__ out)
{
    __shared__ float4 tcor[NQ];     // x1, x2, y1, y2
    __shared__ float  tarea[NQ];
    __shared__ int    lidx[SPB];
    __shared__ float  sconf0;
    __shared__ float2 sres[SPB];    // per-row (bce_mean, conf)
    __shared__ int    winner;
    __shared__ float  fr[12];       // finalize cross-wave reduce

    const int bx  = blockIdx.x;     // 0..56
    const int b   = blockIdx.y;     // 0..15
    const int tid = threadIdx.x;

    // stage teacher boxes of batch b
    const float4* tb = (const float4*)(t_boxes + b * NQ * 4);
    for (int i = tid; i < NQ; i += 256) {
        float4 t = tb[i];
        float hw = t.z * 0.5f, hh = t.w * 0.5f;
        tcor[i]  = make_float4(t.x - hw, t.x + hw, t.y - hh, t.y + hh);
        tarea[i] = t.z * t.w;
    }
    // conf0[b] (one wave; redundant per block but cheap)
    if (tid < 64) {
        const float* tl = t_logits + b * NQ * NC;   // teacher row 0 of batch b
        float m = tl[tid];
        if (tid < NC - 64) m = fmaxf(m, tl[tid + 64]);
        for (int s = 32; s >= 1; s >>= 1) m = fmaxf(m, __shfl_xor(m, s, 64));
        if (tid == 0) sconf0 = (sigm(m) > 0.2f) ? 1.0f : 0.0f;
    }
    __syncthreads();

    // ---- argmax IoU over 900 teachers; 16 lanes per student (R5 numerics, exact) ----
    const int s  = tid >> 4;        // 0..15
    const int tc = tid & 15;        // teacher phase
    const int sq = bx * SPB + s;
    const bool act = (sq < NQ);
    float best = -1.0f; int bidx = 0;
    float4 sb = make_float4(0.f, 0.f, 0.f, 0.f);
    float sx1 = 0.f, sx2 = 0.f, sy1 = 0.f, sy2 = 0.f, sarea = 0.f;
    if (act) {
        sb = ((const float4*)(s_boxes + b * NQ * 4))[sq];
        float shw = sb.z * 0.5f, shh = sb.w * 0.5f;
        sx1 = sb.x - shw; sx2 = sb.x + shw;
        sy1 = sb.y - shh; sy2 = sb.y + shh;
        sarea = sb.z * sb.w;
        #pragma unroll 4
        for (int i = 0; i < 57; ++i) {
            int t = tc + (i << 4);
            if (t < NQ) {
                float4 c = tcor[t];
                float iw = fminf(sx2, c.y) - fmaxf(sx1, c.x);
                float ih = fminf(sy2, c.w) - fmaxf(sy1, c.z);
                float inter = fmaxf(iw, 0.0f) * fmaxf(ih, 0.0f);
                float uni = sarea + tarea[t] - inter + EPSV;
                float iou = inter * __frcp_rn(uni);
                if (iou > best) { best = iou; bidx = t; }  // strictly greater
            }
        }
    }
    // combine 16 phases; ties -> lower index (argmax first-occurrence)
    for (int m = 1; m <= 8; m <<= 1) {
        float ov = __shfl_xor(best, m, 64);
        int   oi = __shfl_xor(bidx, m, 64);
        if (ov > best || (ov == best && oi < bidx)) { best = ov; bidx = oi; }
    }
    if (act && tc == 0) {
        int o = b * NQ + sq;
        lidx[s] = bidx;
        atomicAdd(&g_cnt[b * NQ + bidx], 1);    // scatter-count (int, deterministic)
        // L1 and (1 - GIoU) vs teacher box 0 (exact divides like ref)
        float4 t0 = tb[0];
        float4 c  = tcor[0];
        float iw = fminf(sx2, c.y) - fmaxf(sx1, c.x);
        float ih = fminf(sy2, c.w) - fmaxf(sy1, c.z);
        float inter = fmaxf(iw, 0.0f) * fmaxf(ih, 0.0f);
        float uni = sarea + tarea[0] - inter + EPSV;
        float iou = inter / uni;
        float cw = fmaxf(sx2, c.y) - fminf(sx1, c.x);
        float ch = fmaxf(sy2, c.w) - fminf(sy1, c.z);
        float carea = cw * ch + EPSV;
        float giou1 = 1.0f - (iou - (carea - uni) / carea);
        float l1 = fabsf(sb.x - t0.x) + fabsf(sb.y - t0.y) +
                   fabsf(sb.z - t0.z) + fabsf(sb.w - t0.w);
        float v = 0.0f;
        if (sconf0 > 0.0f && best > IOU_THR) v = 5.0f * l1 + 2.0f * giou1;
        g_v[o] = v;
    }
    __syncthreads();

    // ---- BCE + conf: 16-lane group per row; float4 + scalar loads ----
    const int wv  = tid >> 6, lane = tid & 63;
    const int grp = lane >> 4, tc2 = lane & 15;
    const int s2  = wv * 4 + grp;              // 0..15
    const int sq2 = bx * SPB + s2;
    if (sq2 < NQ) {
        int row = b * NQ + sq2;
        int j   = lidx[s2];                    // flat idx -> batch-0 teacher row (ref quirk)
        const float* srow = s_logits + row * NC;
        const float* trow = t_logits + row * NC;
        const float* grow = t_logits + j * NC;
        float4 sv = *(const float4*)(srow + tc2 * 4);
        float4 tv = *(const float4*)(trow + tc2 * 4);
        float4 gv = *(const float4*)(grow + tc2 * 4);
        float  s4 = srow[64 + tc2];
        float  t4 = trow[64 + tc2];
        float  g4 = grow[64 + tc2];
        float bce = 0.f;
        {
            float se[5] = {sv.x, sv.y, sv.z, sv.w, s4};
            float ge[5] = {gv.x, gv.y, gv.z, gv.w, g4};
            #pragma unroll
            for (int e = 0; e < 5; ++e) {
                float s0 = se[e], g0 = ge[e];
                bce += fmaxf(s0, 0.f) + __logf(1.0f + __expf(-fabsf(s0)))
                     - s0 * __builtin_amdgcn_rcpf(1.0f + __expf(-g0));
            }
        }
        float tmax = fmaxf(fmaxf(fmaxf(tv.x, tv.y), fmaxf(tv.z, tv.w)), t4);
        for (int m = 8; m >= 1; m >>= 1) {
            bce  += __shfl_xor(bce, m, 64);
            tmax  = fmaxf(tmax, __shfl_xor(tmax, m, 64));
        }
        if (tc2 == 0)
            sres[s2] = make_float2(bce * (1.0f / (float)NC),
                                   (sigm(tmax) > 0.2f) ? 1.0f : 0.0f);
    }
    __syncthreads();
    if (tid < 64) {
        float bs = 0.f, ca = 0.f;
        if (tid < SPB) { float2 p = sres[tid]; bs = p.x; ca = p.y; }
        for (int m = 32; m >= 1; m >>= 1) {
            bs += __shfl_xor(bs, m, 64);
            ca  = fmaxf(ca, __shfl_xor(ca, m, 64));
        }
        if (tid == 0) g_part[b * CHB + bx] = make_float2(bs, ca);
    }

    // ---- last-block ticket (CUB pattern): only final arriver proceeds ----
    __syncthreads();
    if (tid == 0) {
        __threadfence();    // release this block's g_v/g_part stores to device scope
        int old = __hip_atomic_fetch_add(done, 1, __ATOMIC_ACQ_REL, __HIP_MEMORY_SCOPE_AGENT);
        winner = (old == NBLK - 1) ? 1 : 0;
    }
    __syncthreads();
    if (!winner) return;
    __threadfence();        // acquire: see all other blocks' stores

    // ---- finalize: 256 threads, coalesced ----
    float bs = 0.f, ca = 0.f, vs = 0.f;
    for (int i = tid; i < NBLK; i += 256) {
        float2 p = g_part[i];
        bs += p.x; ca = fmaxf(ca, p.y);
    }
    for (int i = tid; i < NB * NQ; i += 256)
        vs += (float)g_cnt[i] * g_v[i];          // coalesced, no indirection
    for (int m = 32; m >= 1; m >>= 1) {
        bs += __shfl_xor(bs, m, 64);
        vs += __shfl_xor(vs, m, 64);
        ca  = fmaxf(ca, __shfl_xor(ca, m, 64));
    }
    if ((tid & 63) == 0) {
        int w = tid >> 6;
        fr[w] = bs; fr[4 + w] = vs; fr[8 + w] = ca;
    }
    __syncthreads();
    if (tid == 0) {
        float sb2 = fr[0] + fr[1] + fr[2] + fr[3];
        float sv2 = fr[4] + fr[5] + fr[6] + fr[7];
        float sc2 = fmaxf(fmaxf(fr[8], fr[9]), fmaxf(fr[10], fr[11]));
        float tn = (float)tn_p[0];
        out[0] = (sc2 > 0.f) ? (sv2 + sb2) / tn : 0.0f;
    }
}

extern "C" void kernel_launch(void* const* d_in, const int* in_sizes, int n_in,
                              void* d_out, int out_size, void* d_ws, size_t ws_size,
                              hipStream_t stream) {
    const float* s_logits = (const float*)d_in[0];
    const float* s_boxes  = (const float*)d_in[1];
    const float* t_logits = (const float*)d_in[2];
    const float* t_boxes  = (const float*)d_in[3];
    const int*   tn       = (const int*)d_in[4];
    float* out = (float*)d_out;

    char* ws = (char*)d_ws;
    int*    g_cnt  = (int*)(ws);              // 14400 i32 @ 0       (zeroed per call)
    int*    done   = (int*)(ws + 57600);      // 1 i32     @ 57600   (zeroed per call)
    float*  g_v    = (float*)(ws + 57664);    // 14400 f32
    float2* g_part = (float2*)(ws + 115264);  // 912 float2

    hipMemsetAsync(ws, 0, 57664, stream);
    k_main<<<dim3(CHB, NB), 256, 0, stream>>>(s_logits, s_boxes, t_logits, t_boxes, tn,
                                              g_cnt, done, g_v, g_part, out);
}

// Round 8
// 30.561 us; speedup vs baseline: 2.2933x; 2.2933x over previous
//
#include <hip/hip_runtime.h>
#include <math.h>

#define NB 16
#define NQ 900
#define NQP 928             // padded teacher count (29*32)
#define NC 80
#define EPSV 1e-7f
#define IOU_THR 0.1f
#define SPB 8               // students per block
#define CHB 113             // blocks per batch (113*8 = 904 >= 900)
#define NBLK (NB * CHB)     // 1808

__device__ __forceinline__ float sigm(float x) { return 1.0f / (1.0f + __expf(-x)); }

// ---- K1: per-(b, 8 students): IoU argmax (32-lane split) + cnt scatter + BCE/conf ----
__global__ __launch_bounds__(256) void k_main(
    const float* __restrict__ s_logits,
    const float* __restrict__ s_boxes,
    const float* __restrict__ t_logits,
    const float* __restrict__ t_boxes,
    int*    __restrict__ g_cnt,     // [NB*NQ] zeroed by memset node; cnt[b,j] += 1
    float*  __restrict__ g_v,       // [NB*NQ] flag-gated 5*l1+2*(1-giou), else 0
    float2* __restrict__ g_part)    // [NBLK]  (bce_sum, conf_any)
{
    __shared__ float4 tcor[NQP];    // x1, x2, y1, y2 (pad: impossible boxes -> iou 0)
    __shared__ float  tarea[NQP];
    __shared__ int    lidx[SPB];
    __shared__ float  sconf0;
    __shared__ float2 sres[SPB];    // per-row (bce_mean, conf)

    const int bx  = blockIdx.x;     // 0..112
    const int b   = blockIdx.y;     // 0..15
    const int tid = threadIdx.x;

    if (tid < SPB) sres[tid] = make_float2(0.f, 0.f);

    // stage teacher boxes of batch b (padded to 928)
    const float4* tb = (const float4*)(t_boxes + b * NQ * 4);
    for (int i = tid; i < NQP; i += 256) {
        if (i < NQ) {
            float4 t = tb[i];
            float hw = t.z * 0.5f, hh = t.w * 0.5f;
            tcor[i]  = make_float4(t.x - hw, t.x + hw, t.y - hh, t.y + hh);
            tarea[i] = t.z * t.w;
        } else {
            tcor[i]  = make_float4(2e9f, -2e9f, 2e9f, -2e9f);  // inter == 0 exactly
            tarea[i] = 1.0f;
        }
    }
    // conf0[b] (one wave; redundant per block but cheap)
    if (tid < 64) {
        const float* tl = t_logits + b * NQ * NC;   // teacher row 0 of batch b
        float m = tl[tid];
        if (tid < NC - 64) m = fmaxf(m, tl[tid + 64]);
        for (int s = 32; s >= 1; s >>= 1) m = fmaxf(m, __shfl_xor(m, s, 64));
        if (tid == 0) sconf0 = (sigm(m) > 0.2f) ? 1.0f : 0.0f;
    }
    __syncthreads();

    // ---- argmax IoU over 900(+pad) teachers; 32 lanes per student ----
    const int s  = tid >> 5;        // 0..7
    const int tc = tid & 31;        // teacher phase
    const int sq = bx * SPB + s;
    const bool act = (sq < NQ);
    float best = -1.0f; int bidx = 0;
    float4 sb = make_float4(0.f, 0.f, 0.f, 0.f);
    float sx1 = 0.f, sx2 = 0.f, sy1 = 0.f, sy2 = 0.f, sarea = 0.f;
    if (act) {
        sb = ((const float4*)(s_boxes + b * NQ * 4))[sq];
        float shw = sb.z * 0.5f, shh = sb.w * 0.5f;
        sx1 = sb.x - shw; sx2 = sb.x + shw;
        sy1 = sb.y - shh; sy2 = sb.y + shh;
        sarea = sb.z * sb.w;
        #pragma unroll 4
        for (int i = 0; i < 29; ++i) {
            int t = tc + (i << 5);      // < 928, no bounds branch (pads: iou == 0)
            float4 c = tcor[t];
            float iw = fminf(sx2, c.y) - fmaxf(sx1, c.x);
            float ih = fminf(sy2, c.w) - fmaxf(sy1, c.z);
            float inter = fmaxf(iw, 0.0f) * fmaxf(ih, 0.0f);
            float uni = sarea + tarea[t] - inter + EPSV;
            float iou = inter * __frcp_rn(uni);
            if (iou > best) { best = iou; bidx = t; }  // strictly greater
        }
    }
    // combine 32 phases (xor within 32-lane groups); ties -> lower teacher index
    for (int m = 1; m <= 16; m <<= 1) {
        float ov = __shfl_xor(best, m, 64);
        int   oi = __shfl_xor(bidx, m, 64);
        if (ov > best || (ov == best && oi < bidx)) { best = ov; bidx = oi; }
    }
    if (act && tc == 0) {
        int o = b * NQ + sq;
        lidx[s] = bidx;
        atomicAdd(&g_cnt[b * NQ + bidx], 1);    // relaxed int scatter (deterministic)
        // L1 and (1 - GIoU) vs teacher box 0 (exact divides like ref)
        float4 t0 = tb[0];
        float4 c  = tcor[0];
        float iw = fminf(sx2, c.y) - fmaxf(sx1, c.x);
        float ih = fminf(sy2, c.w) - fmaxf(sy1, c.z);
        float inter = fmaxf(iw, 0.0f) * fmaxf(ih, 0.0f);
        float uni = sarea + tarea[0] - inter + EPSV;
        float iou = inter / uni;
        float cw = fmaxf(sx2, c.y) - fminf(sx1, c.x);
        float ch = fmaxf(sy2, c.w) - fminf(sy1, c.z);
        float carea = cw * ch + EPSV;
        float giou1 = 1.0f - (iou - (carea - uni) / carea);
        float l1 = fabsf(sb.x - t0.x) + fabsf(sb.y - t0.y) +
                   fabsf(sb.z - t0.z) + fabsf(sb.w - t0.w);
        float v = 0.0f;
        if (sconf0 > 0.0f && best > IOU_THR) v = 5.0f * l1 + 2.0f * giou1;
        g_v[o] = v;
    }
    __syncthreads();

    // ---- BCE + conf: 16-lane group per row; rows 0..7 (groups 8..15 idle) ----
    const int wv  = tid >> 6, lane = tid & 63;
    const int grp = lane >> 4, tc2 = lane & 15;
    const int r   = wv * 4 + grp;              // 0..15
    const int sq2 = bx * SPB + r;
    if (r < SPB && sq2 < NQ) {
        int row = b * NQ + sq2;
        int j   = lidx[r];                     // flat idx -> batch-0 teacher row (ref quirk)
        const float* srow = s_logits + row * NC;
        const float* trow = t_logits + row * NC;
        const float* grow = t_logits + j * NC;
        float4 svv = *(const float4*)(srow + tc2 * 4);
        float4 tvv = *(const float4*)(trow + tc2 * 4);
        float4 gvv = *(const float4*)(grow + tc2 * 4);
        float  s4 = srow[64 + tc2];
        float  t4 = trow[64 + tc2];
        float  g4 = grow[64 + tc2];
        float bce = 0.f;
        {
            float se[5] = {svv.x, svv.y, svv.z, svv.w, s4};
            float ge[5] = {gvv.x, gvv.y, gvv.z, gvv.w, g4};
            #pragma unroll
            for (int e = 0; e < 5; ++e) {
                float s0 = se[e], g0 = ge[e];
                bce += fmaxf(s0, 0.f) + __logf(1.0f + __expf(-fabsf(s0)))
                     - s0 * __builtin_amdgcn_rcpf(1.0f + __expf(-g0));
            }
        }
        float tmax = fmaxf(fmaxf(fmaxf(tvv.x, tvv.y), fmaxf(tvv.z, tvv.w)), t4);
        for (int m = 8; m >= 1; m >>= 1) {
            bce  += __shfl_xor(bce, m, 64);
            tmax  = fmaxf(tmax, __shfl_xor(tmax, m, 64));
        }
        if (tc2 == 0)
            sres[r] = make_float2(bce * (1.0f / (float)NC),
                                  (sigm(tmax) > 0.2f) ? 1.0f : 0.0f);
    }
    __syncthreads();
    if (tid < 64) {
        float bs = 0.f, ca = 0.f;
        if (tid < SPB) { float2 p = sres[tid]; bs = p.x; ca = p.y; }
        for (int m = 32; m >= 1; m >>= 1) {
            bs += __shfl_xor(bs, m, 64);
            ca  = fmaxf(ca, __shfl_xor(ca, m, 64));
        }
        if (tid == 0) g_part[b * CHB + bx] = make_float2(bs, ca);
    }
}

// ---- K2: single block — coalesced cnt·v dot + partial reduce + finalize ----
__global__ __launch_bounds__(1024) void k_final(
    const int*    __restrict__ g_cnt,
    const float*  __restrict__ g_v,
    const float2* __restrict__ g_part,
    const int*    __restrict__ tn_p,
    float* __restrict__ out)
{
    const int tid = threadIdx.x;
    float bs = 0.f, ca = 0.f;
    for (int i = tid; i < NBLK; i += 1024) {
        float2 p = g_part[i];
        bs += p.x; ca = fmaxf(ca, p.y);
    }
    float vs = 0.f;
    #pragma unroll
    for (int k = 0; k < 15; ++k) {
        int i = tid + k * 1024;
        if (i < NB * NQ) vs += (float)g_cnt[i] * g_v[i];   // coalesced, no indirection
    }
    __shared__ float rb[16], rv[16], rc[16];
    const int wv = tid >> 6, lane = tid & 63;
    for (int m = 32; m >= 1; m >>= 1) {
        bs += __shfl_xor(bs, m, 64);
        vs += __shfl_xor(vs, m, 64);
        ca  = fmaxf(ca, __shfl_xor(ca, m, 64));
    }
    if (lane == 0) { rb[wv] = bs; rv[wv] = vs; rc[wv] = ca; }
    __syncthreads();
    if (tid == 0) {
        float sb = 0.f, sv = 0.f, sc = 0.f;
        for (int k = 0; k < 16; ++k) { sb += rb[k]; sv += rv[k]; sc = fmaxf(sc, rc[k]); }
        float tn = (float)tn_p[0];
        out[0] = (sc > 0.f) ? (sv + sb) / tn : 0.0f;
    }
}

extern "C" void kernel_launch(void* const* d_in, const int* in_sizes, int n_in,
                              void* d_out, int out_size, void* d_ws, size_t ws_size,
                              hipStream_t stream) {
    const float* s_logits = (const float*)d_in[0];
    const float* s_boxes  = (const float*)d_in[1];
    const float* t_logits = (const float*)d_in[2];
    const float* t_boxes  = (const float*)d_in[3];
    const int*   tn       = (const int*)d_in[4];
    float* out = (float*)d_out;

    char* ws = (char*)d_ws;
    int*    g_cnt  = (int*)(ws);              // 14400 i32 @ 0 (zeroed per call)
    float*  g_v    = (float*)(ws + 57600);    // 14400 f32
    float2* g_part = (float2*)(ws + 115200);  // 1808 float2

    hipMemsetAsync(g_cnt, 0, NB * NQ * sizeof(int), stream);
    k_main<<<dim3(CHB, NB), 256, 0, stream>>>(s_logits, s_boxes, t_logits, t_boxes,
                                              g_cnt, g_v, g_part);
    k_final<<<1, 1024, 0, stream>>>(g_cnt, g_v, g_part, tn, out);
}